// Round 7
// baseline (165.769 us; speedup 1.0000x reference)
//
#include <hip/hip_runtime.h>
#include <stdint.h>

#define N_CODES 65536
#define CB_DIM 8
#define B_ROWS 16
#define X_COLS 2048
#define M_ROWS 4096            // 16*2048/8
#define RPB 8                  // rows per block in argmin kernel
#define THREADS 256

// workspace byte offsets (all 16B-aligned); total 2507008 B (same as r1)
#define WS_SCALE 0             // 16 f32
#define WS_IDX   256           // 4096 i32
#define WS_NU    16640         // 32768 f32  (nu = -2*x/scale, flat, x-layout)
#define WS_SUMS  147712        // 65536*8 f32
#define WS_CNT   2244864       // 65536 f32

// distance + min-track for one code against 8 SGPR-resident rows.
// each fma reads exactly one SGPR (nu) -> v_fma_f32 vD, s, v, vD (legal).
#define CODE_BODY(C0, C1, NIDX)                                            \
    {                                                                      \
        float hn = (C0).x * (C0).x;                                        \
        hn = fmaf((C0).y, (C0).y, hn);                                     \
        hn = fmaf((C0).z, (C0).z, hn);                                     \
        hn = fmaf((C0).w, (C0).w, hn);                                     \
        hn = fmaf((C1).x, (C1).x, hn);                                     \
        hn = fmaf((C1).y, (C1).y, hn);                                     \
        hn = fmaf((C1).z, (C1).z, hn);                                     \
        hn = fmaf((C1).w, (C1).w, hn);                                     \
        _Pragma("unroll")                                                  \
        for (int r = 0; r < RPB; r++) {                                    \
            float d = hn;                                                  \
            d = fmaf(nu[r * 8 + 0], (C0).x, d);                            \
            d = fmaf(nu[r * 8 + 1], (C0).y, d);                            \
            d = fmaf(nu[r * 8 + 2], (C0).z, d);                            \
            d = fmaf(nu[r * 8 + 3], (C0).w, d);                            \
            d = fmaf(nu[r * 8 + 4], (C1).x, d);                            \
            d = fmaf(nu[r * 8 + 5], (C1).y, d);                            \
            d = fmaf(nu[r * 8 + 6], (C1).z, d);                            \
            d = fmaf(nu[r * 8 + 7], (C1).w, d);                            \
            if (d < best[r]) { best[r] = d; bidx[r] = (NIDX); }            \
        }                                                                  \
    }

// ---------------- prep: per-row scale + nu = -2*x/scale ----------------
__global__ __launch_bounds__(256) void prep_kernel(const float* __restrict__ x,
                                                   float* __restrict__ scale_out,
                                                   float* __restrict__ nu_out) {
    int row = blockIdx.x;
    int tid = threadIdx.x;
    const float4* xv = (const float4*)(x + row * X_COLS);
    float4 q0 = xv[tid];
    float4 q1 = xv[tid + 256];
    float s = fabsf(q0.x) + fabsf(q0.y) + fabsf(q0.z) + fabsf(q0.w)
            + fabsf(q1.x) + fabsf(q1.y) + fabsf(q1.z) + fabsf(q1.w);
    #pragma unroll
    for (int off = 32; off > 0; off >>= 1) s += __shfl_down(s, off, 64);
    __shared__ float ls[4];
    __shared__ float scale_sh;
    int wave = tid >> 6, lane = tid & 63;
    if (lane == 0) ls[wave] = s;
    __syncthreads();
    if (tid == 0) {
        float t = (ls[0] + ls[1] + ls[2] + ls[3]) * (1.0f / (float)X_COLS);
        scale_sh = t;
        scale_out[row] = t;
    }
    __syncthreads();
    float sc = scale_sh;

    // nu = -2*(x/scale); accum later recovers u = -0.5*nu bit-exactly
    float4 n0, n1;
    n0.x = -2.0f * (q0.x / sc); n0.y = -2.0f * (q0.y / sc);
    n0.z = -2.0f * (q0.z / sc); n0.w = -2.0f * (q0.w / sc);
    n1.x = -2.0f * (q1.x / sc); n1.y = -2.0f * (q1.y / sc);
    n1.z = -2.0f * (q1.z / sc); n1.w = -2.0f * (q1.w / sc);
    float4* nv = (float4*)(nu_out + row * X_COLS);
    nv[tid] = n0;
    nv[tid + 256] = n1;
}

// ---------------- argmin: nu via block-uniform loads (-> s_load) ----------
// nu_g address depends only on blockIdx, pointer is const __restrict__, and
// this kernel's stores can't alias it => uniform-load annotation => SMEM
// s_load, values SGPR-resident for the whole loop. No asm (r6 failure:
// readfirstlane hazard across asm boundary => stale nu, absmax 2.8).
__global__ __launch_bounds__(256, 2) void argmin_kernel(const float* __restrict__ cb,
                                                        const float* __restrict__ nu_g,
                                                        int* __restrict__ indices,
                                                        float* __restrict__ sums,
                                                        float* __restrict__ counts) {
    int tid = threadIdx.x;
    int m0 = blockIdx.x * RPB;

    const float* nup = nu_g + (size_t)m0 * CB_DIM;     // block-uniform
    float nu[RPB * CB_DIM];
    #pragma unroll
    for (int i = 0; i < RPB * CB_DIM; i++) nu[i] = nup[i];

    float best[RPB];
    int   bidx[RPB];
    #pragma unroll
    for (int r = 0; r < RPB; r++) { best[r] = 3.4e38f; bidx[r] = 0; }

    // ---- hot loop: 2 codes/iter, register double-prefetch, peeled tail ----
    const float4* cp = (const float4*)cb;
    float4 a0 = cp[2 * tid],             a1 = cp[2 * tid + 1];
    float4 b0 = cp[2 * (tid + THREADS)], b1 = cp[2 * (tid + THREADS) + 1];

    int n = tid;
    for (int k = 0; k < 127; k++, n += 2 * THREADS) {
        float4 pa0 = cp[2 * (n + 2 * THREADS)], pa1 = cp[2 * (n + 2 * THREADS) + 1];
        CODE_BODY(a0, a1, n)
        float4 pb0 = cp[2 * (n + 3 * THREADS)], pb1 = cp[2 * (n + 3 * THREADS) + 1];
        CODE_BODY(b0, b1, n + THREADS)
        a0 = pa0; a1 = pa1; b0 = pb0; b1 = pb1;
    }
    CODE_BODY(a0, a1, n)
    CODE_BODY(b0, b1, n + THREADS)

    // ---- cross-thread reduce: (sortable(dist)<<32)|idx, u64-min ----
    __shared__ unsigned long long red[RPB][THREADS];   // 16 KB
    #pragma unroll
    for (int r = 0; r < RPB; r++) {
        unsigned int b = __float_as_uint(best[r]);
        unsigned int k = b ^ ((unsigned int)((int)b >> 31) | 0x80000000u);
        red[r][tid] = ((unsigned long long)k << 32) | (unsigned int)bidx[r];
    }
    for (int t = THREADS / 2; t > 0; t >>= 1) {
        __syncthreads();
        if (tid < t) {
            #pragma unroll
            for (int r = 0; r < RPB; r++) {
                unsigned long long a = red[r][tid], c = red[r][tid + t];
                if (c < a) red[r][tid] = c;
            }
        }
    }
    __syncthreads();

    // indices + zero sums/counts at selected codes (kernel boundary orders
    // the zeros before accum; duplicate zero-writes are benign)  [r4 tail]
    if (tid < RPB) {
        int idx = (int)(red[tid][0] & 0xFFFFFFFFull);
        indices[m0 + tid] = idx;
        counts[idx] = 0.f;
        float4 z = make_float4(0.f, 0.f, 0.f, 0.f);
        float4* sp = (float4*)(sums + (size_t)idx * CB_DIM);
        sp[0] = z;
        sp[1] = z;
    }
}

// ---------------- segment-sum via atomics (u = -0.5*nu, exact) ----------
__global__ __launch_bounds__(256) void accum_kernel(const int* __restrict__ indices,
                                                    const float* __restrict__ nu_g,
                                                    float* __restrict__ sums,
                                                    float* __restrict__ counts) {
    int m = blockIdx.x * blockDim.x + threadIdx.x;
    if (m < M_ROWS) {
        int idx = indices[m];
        atomicAdd(&counts[idx], 1.0f);
        #pragma unroll
        for (int k = 0; k < CB_DIM; k++)
            atomicAdd(&sums[(size_t)idx * CB_DIM + k], -0.5f * nu_g[m * CB_DIM + k]);
    }
}

// ---------------- gather + rescale ----------------
__global__ __launch_bounds__(256) void gather_kernel(const int* __restrict__ indices,
                                                     const float* __restrict__ sums,
                                                     const float* __restrict__ counts,
                                                     const float* __restrict__ scale,
                                                     float* __restrict__ out) {
    int e = blockIdx.x * blockDim.x + threadIdx.x;     // 0..32767
    if (e < B_ROWS * X_COLS) {
        int m = e >> 3, k = e & 7;
        int idx = indices[m];
        float c = counts[idx];
        c = c < 1.f ? 1.f : c;
        out[e] = scale[e >> 11] * (sums[(size_t)idx * CB_DIM + k] / c);
    }
}

extern "C" void kernel_launch(void* const* d_in, const int* in_sizes, int n_in,
                              void* d_out, int out_size, void* d_ws, size_t ws_size,
                              hipStream_t stream) {
    const float* x  = (const float*)d_in[0];           // [16,2048]
    const float* cb = (const float*)d_in[1];           // [65536,8]
    char* ws = (char*)d_ws;
    float* scale   = (float*)(ws + WS_SCALE);
    int*   indices = (int*)(ws + WS_IDX);
    float* nu      = (float*)(ws + WS_NU);
    float* sums    = (float*)(ws + WS_SUMS);
    float* counts  = (float*)(ws + WS_CNT);
    float* out     = (float*)d_out;

    prep_kernel  <<<B_ROWS, 256, 0, stream>>>(x, scale, nu);
    argmin_kernel<<<M_ROWS / RPB, 256, 0, stream>>>(cb, nu, indices, sums, counts);
    accum_kernel <<<M_ROWS / 256, 256, 0, stream>>>(indices, nu, sums, counts);
    gather_kernel<<<(B_ROWS * X_COLS) / 256, 256, 0, stream>>>(indices, sums, counts, scale, out);
}